// Round 16
// baseline (252.506 us; speedup 1.0000x reference)
//
#include <hip/hip_runtime.h>
#include <hip/hip_cooperative_groups.h>
#include <stdint.h>

namespace cg = cooperative_groups;

#define N_IMG 2
#define A_NUM 15
#define HH 200
#define WW 200
#define HW 40000          // HH*WW
#define K_TOT 600000      // A_NUM*HW
#define K_TOT4 150000     // K_TOT/4
#define P_PRE 6000
#define R_POST 1000
#define NMS_T 0.7f
#define MIN_SZ 16.0f
#define FSTRIDE 16.0f
#define BBOX_CLIP 4.135166556742356f   // log(1000/16)
#define CAND_CAP 8192
#define NWORDS 94         // ceil(6000/64)
#define BINS 4096
// k_mask blocks per image: sum over ci of ceil((NWORDS-ci)/8) = 600
#define MASK_BLOCKS 600
// words to zero each launch: histA + histB + meta (contiguous at ws base)
#define ZERO_WORDS (N_IMG * BINS * 2 + N_IMG * 16)   // 16416
// Exact threshold: fl32(inter/union) > 0.7f  <=>  inter/union >= MID_T
#define MID_T 0.7000000178813934326171875

typedef unsigned long long u64;
typedef uint32_t u32;

__device__ __forceinline__ u32 fkey(float s) {
    return __float_as_uint(s) | 0x80000000u;
}

// IoU decision, bit-identical to fl32(inter/(ar+arj-inter)) > 0.7f.
__device__ __forceinline__ bool iou_gt(float ar, float arj,
                                       const float4& bi, const float4& bj) {
    float xx1 = fmaxf(bi.x, bj.x);
    float yy1 = fmaxf(bi.y, bj.y);
    float xx2 = fminf(bi.z, bj.z);
    float yy2 = fminf(bi.w, bj.w);
    float iw = fmaxf(xx2 - xx1 + 1.0f, 0.0f);
    float ih = fmaxf(yy2 - yy1 + 1.0f, 0.0f);
    float inter = iw * ih;
    float uni = (ar + arj) - inter;          // same op order as reference
    return (double)inter >= MID_T * (double)uni;
}

// ================= cooperative front-end =================
// zero -> histA -> findA -> (histB fallback) -> compact -> rank+decode,
// fused with grid.sync() instead of 6 separate dispatches.
// 128 blocks x 256 threads, 64 KiB LDS (aliased per phase).
__global__ void __launch_bounds__(256) k_front(
        const float* __restrict__ sc, const float* __restrict__ bbox,
        const float* __restrict__ iminfo, const float* __restrict__ anchors,
        u32* __restrict__ histA, u32* __restrict__ histB, u32* __restrict__ meta,
        u64* __restrict__ cand, float* __restrict__ topk_sc,
        float4* __restrict__ bbox4, u32* __restrict__ bval) {
    cg::grid_group grid = cg::this_grid();
    __shared__ u64 sk[CAND_CAP];                 // 64 KiB, phase-aliased
    u32* h     = (u32*)sk;                       // u32 [0, 4096)
    u32* part  = (u32*)sk + BINS;                // u32 [4096, 4352)
    u32* wtot  = (u32*)sk + BINS + 256;          // 4 entries
    u32* baseS = (u32*)sk + BINS + 260;          // 1 entry
    u32* pr    = (u32*)sk + 16000;               // 256 entries (above key region)
    int bid = blockIdx.x;
    int tid = threadIdx.x;
    int lane = tid & 63, w = tid >> 6;
    int n = bid >> 6;                            // 64 blocks per image
    int bl = bid & 63;
    const float4* s4 = (const float4*)(sc + (size_t)n * K_TOT);

    // ---- phase Z: zero hist buffers + meta ----
    {
        int i = bid * 256 + tid;                 // 32768 threads >= 16416
        if (i < ZERO_WORDS) histA[i] = 0u;       // histA is ws base; contiguous
    }
    grid.sync();

    // ---- phase H: 12-bit histogram, LDS-privatized ----
    for (int i = tid; i < BINS; i += 256) h[i] = 0;
    __syncthreads();
    for (int i = bl * 256 + tid; i < K_TOT4; i += 64 * 256) {
        float4 v = s4[i];
        atomicAdd(&h[fkey(v.x) >> 20], 1u);
        atomicAdd(&h[fkey(v.y) >> 20], 1u);
        atomicAdd(&h[fkey(v.z) >> 20], 1u);
        atomicAdd(&h[fkey(v.w) >> 20], 1u);
    }
    __syncthreads();
    for (int i = tid; i < BINS; i += 256) {
        u32 v = h[i];
        if (v) atomicAdd(&histA[n * BINS + i], v);
    }
    grid.sync();

    // ---- phase F: findA (block 0, both images; plain loads after sync) ----
    if (bid == 0) {
        for (int im = 0; im < N_IMG; ++im) {
            u32* hh = histA + im * BINS;
            u32 s = 0;
            for (int b = tid * 16; b < tid * 16 + 16; ++b) s += hh[b];
            part[tid] = s;
            __syncthreads();
            if (tid == 0) {
                u32 cum = 0; int seg = 255;
                for (; seg > 0; --seg) {
                    if (cum + part[seg] >= P_PRE) break;
                    cum += part[seg];
                }
                u32 cgt = cum; int bA = seg * 16; u32 hbA = 0;
                for (int b = seg * 16 + 15; b >= seg * 16; --b) {
                    u32 hb = hh[b];
                    if (cgt + hb >= P_PRE) { bA = b; hbA = hb; break; }
                    cgt += hb;
                }
                meta[im * 16 + 0] = (u32)bA;
                meta[im * 16 + 1] = cgt;
                if (cgt + hbA <= CAND_CAP) {
                    meta[im * 16 + 2] = ((u32)bA) << 12;   // pass-A-only threshold
                    meta[im * 16 + 8] = 0u;
                } else {
                    meta[im * 16 + 8] = 1u;                // need pass B
                }
            }
            __syncthreads();
        }
    }
    grid.sync();

    // ---- optional pass B (grid-uniform branch; never taken for this data) ----
    bool needB = (meta[8] != 0u) || (meta[16 + 8] != 0u);
    if (needB) {
        bool mine = meta[n * 16 + 8] != 0u;
        for (int i = tid; i < BINS; i += 256) h[i] = 0;
        __syncthreads();
        if (mine) {
            u32 bA = meta[n * 16 + 0];
            for (int i = bl * 256 + tid; i < K_TOT4; i += 64 * 256) {
                float4 v = s4[i];
                u32 k0 = fkey(v.x), k1 = fkey(v.y), k2 = fkey(v.z), k3 = fkey(v.w);
                if ((k0 >> 20) == bA) atomicAdd(&h[(k0 >> 8) & 0xFFFu], 1u);
                if ((k1 >> 20) == bA) atomicAdd(&h[(k1 >> 8) & 0xFFFu], 1u);
                if ((k2 >> 20) == bA) atomicAdd(&h[(k2 >> 8) & 0xFFFu], 1u);
                if ((k3 >> 20) == bA) atomicAdd(&h[(k3 >> 8) & 0xFFFu], 1u);
            }
        }
        __syncthreads();
        if (mine)
            for (int i = tid; i < BINS; i += 256) {
                u32 v = h[i];
                if (v) atomicAdd(&histB[n * BINS + i], v);
            }
        grid.sync();
        if (bid == 0) {
            for (int im = 0; im < N_IMG; ++im) {
                if (meta[im * 16 + 8] == 0u) continue;
                u32* hh = histB + im * BINS;
                u32 s = 0;
                for (int b = tid * 16; b < tid * 16 + 16; ++b) s += hh[b];
                part[tid] = s;
                __syncthreads();
                if (tid == 0) {
                    u32 cum = meta[im * 16 + 1];
                    int seg = 255;
                    for (; seg > 0; --seg) {
                        if (cum + part[seg] >= P_PRE) break;
                        cum += part[seg];
                    }
                    int bB = seg * 16;
                    for (int b = seg * 16 + 15; b >= seg * 16; --b) {
                        u32 hb = hh[b];
                        if (cum + hb >= P_PRE) { bB = b; break; }
                        cum += hb;
                    }
                    meta[im * 16 + 2] = (meta[im * 16 + 0] << 12) | (u32)bB;
                }
                __syncthreads();
            }
        }
        grid.sync();
    }

    // ---- phase C: compact (block-aggregated allocation, wave scan) ----
    {
        u32 thr = meta[n * 16 + 2];
        const int ITERS = (K_TOT4 + 64 * 256 - 1) / (64 * 256);   // 10, uniform
        for (int it = 0; it < ITERS; ++it) {
            int i4 = it * (64 * 256) + bl * 256 + tid;
            float vv[4] = {0.f, 0.f, 0.f, 0.f};
            u32 flags = 0;
            if (i4 < K_TOT4) {
                float4 v = s4[i4];
                vv[0] = v.x; vv[1] = v.y; vv[2] = v.z; vv[3] = v.w;
                #pragma unroll
                for (int e = 0; e < 4; ++e)
                    if ((fkey(vv[e]) >> 8) >= thr) flags |= 1u << e;
            }
            u32 cnt = (u32)__popc(flags);
            u32 incl = cnt;
            #pragma unroll
            for (int off = 1; off < 64; off <<= 1) {
                u32 v = __shfl_up(incl, (unsigned)off);
                if (lane >= off) incl += v;
            }
            if (lane == 63) wtot[w] = incl;
            __syncthreads();
            if (tid == 0) {
                u32 tot = wtot[0] + wtot[1] + wtot[2] + wtot[3];
                *baseS = atomicAdd(&meta[n * 16 + 3], tot);
            }
            __syncthreads();
            if (flags) {
                u32 wbase = 0;
                for (int i = 0; i < w; ++i) wbase += wtot[i];
                u32 pos = *baseS + wbase + (incl - cnt);
                #pragma unroll
                for (int e = 0; e < 4; ++e) {
                    if ((flags >> e) & 1u) {
                        if (pos < CAND_CAP) {
                            int el = i4 * 4 + e;            // a*HW + h*WW + w order
                            int a = el / HW;
                            int r = el - a * HW;
                            u32 idx = (u32)(r * A_NUM + a); // (h*W+w)*A + a
                            cand[n * CAND_CAP + pos] = ((u64)fkey(vv[e]) << 32) | (u32)(~idx);
                        }
                        pos++;
                    }
                }
            }
            __syncthreads();                    // protect wtot/baseS reuse
        }
    }
    grid.sync();

    // ---- phase R: exact rank (stable desc by unique key) + inline decode ----
    for (int g = bid; g < 2 * (CAND_CAP / 64); g += 128) {
        int n2 = g >> 7;
        int base = (g & 127) * 64;
        u32 cnt = meta[n2 * 16 + 3];
        if (cnt > CAND_CAP) cnt = CAND_CAP;
        if (base >= (int)cnt) continue;          // block-uniform
        int cntPad = (int)((cnt + 7u) & ~7u);
        const u64* cn = cand + (size_t)n2 * CAND_CAP;
        __syncthreads();                         // protect sk reuse
        for (int i = tid; i < cntPad; i += 256)
            sk[i] = (i < (int)cnt) ? cn[i] : 0ull;
        __syncthreads();
        int myi = base + lane;
        u64 mykey = (myi < (int)cnt) ? sk[myi] : 0ull;
        int stride = ((cntPad >> 2) + 7) & ~7;
        int j0 = w * stride;
        int j1 = min(j0 + stride, cntPad);
        int rank = 0;
        for (int j = j0; j < j1; j += 8) {
            u64 k0 = sk[j + 0], k1 = sk[j + 1], k2 = sk[j + 2], k3 = sk[j + 3];
            u64 k4 = sk[j + 4], k5 = sk[j + 5], k6 = sk[j + 6], k7 = sk[j + 7];
            rank += (int)(k0 > mykey) + (int)(k1 > mykey)
                  + (int)(k2 > mykey) + (int)(k3 > mykey)
                  + (int)(k4 > mykey) + (int)(k5 > mykey)
                  + (int)(k6 > mykey) + (int)(k7 > mykey);
        }
        pr[w * 64 + lane] = (u32)rank;
        __syncthreads();
        if (w == 0 && myi < (int)cnt) {
            int r = (int)(pr[lane] + pr[64 + lane] + pr[128 + lane] + pr[192 + lane]);
            if (r < P_PRE) {
                u64 kk = mykey;
                u32 idx = ~(u32)(kk & 0xFFFFFFFFull);
                float score = __uint_as_float((u32)(kk >> 32) ^ 0x80000000u);
                topk_sc[n2 * P_PRE + r] = score;
                int a = (int)(idx % A_NUM);
                int cell = (int)(idx / A_NUM);
                int ww = cell % WW, hh = cell / WW;
                float ax1 = anchors[a * 4 + 0] + FSTRIDE * (float)ww;
                float ay1 = anchors[a * 4 + 1] + FSTRIDE * (float)hh;
                float ax2 = anchors[a * 4 + 2] + FSTRIDE * (float)ww;
                float ay2 = anchors[a * 4 + 3] + FSTRIDE * (float)hh;
                float ws = ax2 - ax1 + 1.0f;
                float hs = ay2 - ay1 + 1.0f;
                float cx = ax1 + 0.5f * ws;
                float cy = ay1 + 0.5f * hs;
                const float* bb = bbox + (size_t)n2 * 4 * A_NUM * HW + hh * WW + ww;
                float dx = bb[(4 * a + 0) * HW];
                float dy = bb[(4 * a + 1) * HW];
                float dw = fminf(bb[(4 * a + 2) * HW], BBOX_CLIP);
                float dh = fminf(bb[(4 * a + 3) * HW], BBOX_CLIP);
                float pcx = dx * ws + cx, pcy = dy * hs + cy;
                float pw = expf(dw) * ws, ph = expf(dh) * hs;
                float x1 = pcx - 0.5f * pw;
                float y1 = pcy - 0.5f * ph;
                float x2 = pcx + 0.5f * pw - 1.0f;
                float y2 = pcy + 0.5f * ph - 1.0f;
                float im_h = iminfo[n2 * 3 + 0], im_w = iminfo[n2 * 3 + 1];
                float iscale = iminfo[n2 * 3 + 2];
                x1 = fminf(fmaxf(x1, 0.0f), im_w - 1.0f);
                y1 = fminf(fmaxf(y1, 0.0f), im_h - 1.0f);
                x2 = fminf(fmaxf(x2, 0.0f), im_w - 1.0f);
                y2 = fminf(fmaxf(y2, 0.0f), im_h - 1.0f);
                float wss = x2 - x1 + 1.0f, hss = y2 - y1 + 1.0f;
                float xc = x1 + wss * 0.5f, yc = y1 + hss * 0.5f;
                float ms = MIN_SZ * iscale;
                bool valid = (wss >= ms) && (hss >= ms) && (xc < im_w) && (yc < im_h);
                float4 b; b.x = x1; b.y = y1; b.z = x2; b.w = y2;
                bbox4[n2 * P_PRE + r] = b;
                bval[n2 * P_PRE + r] = valid ? 1u : 0u;
            }
        }
        __syncthreads();
    }
}

// ---------------- stable partition + area precompute (wave scan) -------------
__global__ void __launch_bounds__(1024) k_partition(
        const float4* __restrict__ bbox4,
        const float* __restrict__ bsc, const u32* __restrict__ bval,
        float4* __restrict__ sbox, float* __restrict__ ssc,
        float* __restrict__ sarea, u32* __restrict__ meta) {
    int n = blockIdx.x;
    int t = threadIdx.x;
    int lane = t & 63, w = t >> 6;
    int base = t * 6;
    u32 cnt = 0;
    if (base < P_PRE)
        for (int e = 0; e < 6; ++e) cnt += bval[n * P_PRE + base + e];
    u32 incl = cnt;
    #pragma unroll
    for (int off = 1; off < 64; off <<= 1) {
        u32 v = __shfl_up(incl, (unsigned)off);
        if (lane >= off) incl += v;
    }
    __shared__ u32 wtot[16];
    if (lane == 63) wtot[w] = incl;
    __syncthreads();
    u32 nv = 0, wbase = 0;
    #pragma unroll
    for (int i = 0; i < 16; ++i) {
        u32 x = wtot[i];
        if (i < w) wbase += x;
        nv += x;
    }
    u32 excl = wbase + (incl - cnt);
    if (t == 0) meta[n * 16 + 4] = nv;
    if (base < P_PRE) {
        u32 vseen = excl;
        for (int e = 0; e < 6; ++e) {
            int g = base + e;
            int src = n * P_PRE + g;
            u32 dst;
            if (bval[src]) { dst = vseen; vseen++; }
            else { dst = nv + (u32)g - vseen; }
            int d = n * P_PRE + (int)dst;
            float4 b = bbox4[src];
            sbox[d] = b;
            ssc[d] = bsc[src];
            sarea[d] = (b.z - b.x + 1.0f) * (b.w - b.y + 1.0f);  // ref expression
        }
    }
}

// ---------------- suppression mask, ci-major with LDS row-panel ----------------
__global__ void __launch_bounds__(256) k_mask(const float4* __restrict__ sbox,
                                              const float* __restrict__ sarea,
                                              u64* __restrict__ mask,
                                              u64* __restrict__ selfmask) {
    int n = blockIdx.y;
    int rem = blockIdx.x;
    int ci = 0;
    while (true) {
        int g = (NWORDS - ci + 7) >> 3;
        if (rem < g) break;
        rem -= g;
        ++ci;
    }
    int cjBase = ci + (rem << 3);
    int lane = threadIdx.x & 63;
    int wv = threadIdx.x >> 6;
    __shared__ float4 sbi[64];
    __shared__ float sar[64];
    const float4* pb = sbox + n * P_PRE;
    const float* pa = sarea + n * P_PRE;
    if (threadIdx.x < 64) {
        int ic = min(ci * 64 + (int)threadIdx.x, P_PRE - 1);
        sbi[threadIdx.x] = pb[ic];
        sar[threadIdx.x] = pa[ic];
    }
    __syncthreads();
    #pragma unroll
    for (int sub = 0; sub < 2; ++sub) {
        int cj = cjBase + wv + sub * 4;
        if (cj >= NWORDS) continue;
        int j = cj * 64 + lane;
        int jc = min(j, P_PRE - 1);
        float4 bj = pb[jc];
        float arj = pa[jc];
        if (cj == ci) {
            u64 sm = 0;
            #pragma unroll 8
            for (int r = 0; r < 64; ++r) {
                bool sup = iou_gt(sar[r], arj, sbi[r], bj) && (r < lane);
                sm |= ((u64)sup) << r;
            }
            if (j < P_PRE) selfmask[(size_t)n * P_PRE + j] = sm;
        } else {
            u64 myword = 0;
            #pragma unroll 8
            for (int r = 0; r < 64; ++r) {
                u64 wrd = __ballot(iou_gt(sar[r], arj, sbi[r], bj));
                if (lane == r) myword = wrd;
            }
            int i = ci * 64 + lane;                // lane holds row i's word
            if (i < P_PRE)
                mask[((size_t)n * P_PRE + i) * NWORDS + cj] = myword;
        }
    }
}

// ---------------- greedy NMS scan: pair-parallel scatter ----------------
__global__ void __launch_bounds__(1024) k_scan(
        const u64* __restrict__ mask, const u64* __restrict__ selfmask,
        const float4* __restrict__ sbox, const float* __restrict__ ssc,
        const u32* __restrict__ meta, float* __restrict__ out) {
    int n = blockIdx.x;
    int tid = threadIdx.x;
    int lane = tid & 63;
    int wv = tid >> 6;
    __shared__ u64 rem[NWORDS];
    __shared__ u64 smb[2][64];
    __shared__ u64 sA;
    __shared__ u32 rowsS[64];
    __shared__ int nkS;
    __shared__ u32 kidx[R_POST];
    __shared__ int keptS;
    u32 nv = meta[n * 16 + 4];
    const u64* mrow = mask + (size_t)n * P_PRE * NWORDS;
    const u64* smk = selfmask + (size_t)n * P_PRE;
    for (int c = tid; c < NWORDS; c += 1024) {
        int b0 = c * 64;
        rem[c] = ((u32)b0 >= nv) ? ~0ull
               : (((u32)(nv - b0) >= 64u) ? 0ull : ((~0ull) << (nv - b0)));
    }
    if (wv == 1) smb[0][lane] = smk[lane];         // chunk 0 selfmask
    if (tid == 0) keptS = 0;
    __syncthreads();
    for (int c = 0; c < NWORDS; ++c) {
        if (wv == 1 && (c + 1) < NWORDS) {
            int j = (c + 1) * 64 + lane;
            smb[(c + 1) & 1][lane] = (j < P_PRE) ? smk[j] : 0ull;
        }
        if (wv == 0) {
            u64 A = ~rem[c];
            if (A) {
                u64 sm = smb[c & 1][lane];
                u64 below = (1ull << lane) - 1ull;
                bool cand = ((A >> lane) & 1ull) != 0ull;
                while (true) {                     // fixed-point greedy closure
                    bool sup = (sm & A & below) != 0ull;
                    u64 nA = __ballot(cand && !sup);
                    if (nA == A) break;
                    A = nA;
                }
                int kept = keptS;                  // wave-uniform read
                if ((A >> lane) & 1ull) {
                    int rk = (int)__popcll(A & below);
                    int pos = kept + rk;
                    if (pos < R_POST) kidx[pos] = (u32)(c * 64 + lane);
                    rowsS[rk] = (u32)lane;
                }
                if (lane == 0) {
                    keptS = kept + (int)__popcll(A);
                    nkS = (int)__popcll(A);
                    sA = A;
                }
            } else if (lane == 0) { sA = 0; nkS = 0; }
        }
        __syncthreads();
        if (keptS >= R_POST) break;                // uniform; prefix property
        if (sA) {
            int colSlot = tid & 127;
            int rg = tid >> 7;                     // 8 row groups
            int col = c + 1 + colSlot;
            int nk = nkS;
            if (col < NWORDS && rg < nk) {
                int jbase = c * 64;
                u64 acc = 0;
                for (int r = rg; r < nk; r += 32) {
                    int r1 = r + 8, r2 = r + 16, r3 = r + 24;
                    u64 v0 = mrow[(size_t)(jbase + (int)rowsS[r]) * NWORDS + col];
                    u64 v1 = (r1 < nk) ? mrow[(size_t)(jbase + (int)rowsS[r1]) * NWORDS + col] : 0ull;
                    u64 v2 = (r2 < nk) ? mrow[(size_t)(jbase + (int)rowsS[r2]) * NWORDS + col] : 0ull;
                    u64 v3 = (r3 < nk) ? mrow[(size_t)(jbase + (int)rowsS[r3]) * NWORDS + col] : 0ull;
                    acc |= v0 | v1 | v2 | v3;
                }
                if (acc) atomicOr(&rem[col], acc);
            }
        }
        __syncthreads();
    }
    __syncthreads();
    int kept = keptS;
    for (int r = tid; r < R_POST; r += 1024) {
        float4 b = make_float4(0.f, 0.f, 0.f, 0.f);
        float s = 0.f;
        if (r < kept) {
            u32 i = kidx[r];
            b = sbox[n * P_PRE + (int)i];
            s = ssc[n * P_PRE + (int)i];
        }
        float* o = out + (size_t)(n * R_POST + r) * 6;
        o[0] = (float)n;                   // batch index NOT masked in reference
        o[1] = b.x; o[2] = b.y; o[3] = b.z; o[4] = b.w; o[5] = s;
    }
}

extern "C" void kernel_launch(void* const* d_in, const int* in_sizes, int n_in,
                              void* d_out, int out_size, void* d_ws, size_t ws_size,
                              hipStream_t stream) {
    const float* scores  = (const float*)d_in[0];
    const float* bbox    = (const float*)d_in[1];
    const float* iminfo  = (const float*)d_in[2];
    const float* anchors = (const float*)d_in[3];
    float* out = (float*)d_out;

    char* ws = (char*)d_ws;
    size_t off = 0;
    u32* histA = (u32*)(ws + off); off += (size_t)N_IMG * BINS * 4;    // 32768
    u32* histB = (u32*)(ws + off); off += (size_t)N_IMG * BINS * 4;    // 32768
    u32* meta  = (u32*)(ws + off); off += (size_t)N_IMG * 16 * 4;      // 128
    u64* cand      = (u64*)(ws + off);   off += (size_t)N_IMG * CAND_CAP * 8;
    float* topk_sc = (float*)(ws + off); off += (size_t)N_IMG * P_PRE * 4;
    float4* bbox4 = (float4*)(ws + off); off += (size_t)N_IMG * P_PRE * 16;
    u32* bval  = (u32*)(ws + off);       off += (size_t)N_IMG * P_PRE * 4;
    float4* sbox = (float4*)(ws + off);  off += (size_t)N_IMG * P_PRE * 16;
    float* ssc = (float*)(ws + off);     off += (size_t)N_IMG * P_PRE * 4;
    float* sarea = (float*)(ws + off);   off += (size_t)N_IMG * P_PRE * 4;
    u64* selfmask = (u64*)(ws + off);    off += (size_t)N_IMG * P_PRE * 8;
    u64* mask = (u64*)(ws + off);        off += (size_t)N_IMG * P_PRE * NWORDS * 8;
    (void)ws_size; (void)in_sizes; (void)n_in; (void)out_size;

    void* args[] = {(void*)&scores, (void*)&bbox, (void*)&iminfo, (void*)&anchors,
                    (void*)&histA, (void*)&histB, (void*)&meta, (void*)&cand,
                    (void*)&topk_sc, (void*)&bbox4, (void*)&bval};
    hipLaunchCooperativeKernel((void*)k_front, dim3(128), dim3(256), args, 0, stream);

    k_partition<<<N_IMG, 1024, 0, stream>>>(bbox4, topk_sc, bval, sbox, ssc, sarea, meta);
    dim3 gMask(MASK_BLOCKS, N_IMG);
    k_mask<<<gMask, 256, 0, stream>>>(sbox, sarea, mask, selfmask);
    k_scan<<<N_IMG, 1024, 0, stream>>>(mask, selfmask, sbox, ssc, meta, out);
}

// Round 17
// 177.206 us; speedup vs baseline: 1.4249x; 1.4249x over previous
//
#include <hip/hip_runtime.h>
#include <stdint.h>

#define N_IMG 2
#define A_NUM 15
#define HH 200
#define WW 200
#define HW 40000          // HH*WW
#define K_TOT 600000      // A_NUM*HW
#define K_TOT4 150000     // K_TOT/4
#define P_PRE 6000
#define R_POST 1000
#define NMS_T 0.7f
#define MIN_SZ 16.0f
#define FSTRIDE 16.0f
#define BBOX_CLIP 4.135166556742356f   // log(1000/16)
#define CAND_CAP 8192
#define NWORDS 94         // ceil(6000/64)
#define BINS 4096
#define HIST_BLK 128      // blocks per image for k_histA/k_histB
// k_mask blocks per image: sum over ci of ceil((NWORDS-ci)/8) = 600
#define MASK_BLOCKS 600
// words to zero each launch: histA + histB + meta
#define ZERO_WORDS (N_IMG * BINS * 2 + N_IMG * 16)   // 16416
// Exact threshold: fl32(inter/union) > 0.7f  <=>  inter/union >= MID_T
#define MID_T 0.7000000178813934326171875

typedef unsigned long long u64;
typedef uint32_t u32;

__device__ __forceinline__ u32 fkey(float s) {
    return __float_as_uint(s) | 0x80000000u;
}

// IoU decision, bit-identical to fl32(inter/(ar+arj-inter)) > 0.7f.
__device__ __forceinline__ bool iou_gt(float ar, float arj,
                                       const float4& bi, const float4& bj) {
    float xx1 = fmaxf(bi.x, bj.x);
    float yy1 = fmaxf(bi.y, bj.y);
    float xx2 = fminf(bi.z, bj.z);
    float yy2 = fminf(bi.w, bj.w);
    float iw = fmaxf(xx2 - xx1 + 1.0f, 0.0f);
    float ih = fmaxf(yy2 - yy1 + 1.0f, 0.0f);
    float inter = iw * ih;
    float uni = (ar + arj) - inter;          // same op order as reference
    return (double)inter >= MID_T * (double)uni;
}

// ---------------- workspace zeroing ----------------
__global__ void k_zero(u32* __restrict__ w) {
    int i = blockIdx.x * 1024 + threadIdx.x;
    if (i < ZERO_WORDS) w[i] = 0u;
}

// ---------------- pass A: 12-bit histogram + last-block findA ----------------
__global__ void k_histA(const float* __restrict__ sc, u32* __restrict__ histA,
                        u32* __restrict__ meta) {
    int n = blockIdx.y;
    __shared__ u32 h[BINS];
    __shared__ u32 part[256];
    __shared__ u32 isLast;
    for (int i = threadIdx.x; i < BINS; i += 256) h[i] = 0;
    __syncthreads();
    const float4* s4 = (const float4*)(sc + (size_t)n * K_TOT);
    for (int i = blockIdx.x * 256 + threadIdx.x; i < K_TOT4; i += HIST_BLK * 256) {
        float4 v = s4[i];
        atomicAdd(&h[fkey(v.x) >> 20], 1u);
        atomicAdd(&h[fkey(v.y) >> 20], 1u);
        atomicAdd(&h[fkey(v.z) >> 20], 1u);
        atomicAdd(&h[fkey(v.w) >> 20], 1u);
    }
    __syncthreads();
    for (int i = threadIdx.x; i < BINS; i += 256) {
        u32 v = h[i];
        if (v) atomicAdd(&histA[n * BINS + i], v);
    }
    __threadfence();
    if (threadIdx.x == 0)
        isLast = (atomicAdd(&meta[6], 1u) == (u32)(HIST_BLK * N_IMG - 1)) ? 1u : 0u;
    __syncthreads();
    if (!isLast) return;
    for (int im = 0; im < N_IMG; ++im) {
        u32* hh = histA + im * BINS;
        u32 s = 0;
        for (int b = threadIdx.x * 16; b < threadIdx.x * 16 + 16; ++b)
            s += atomicAdd(&hh[b], 0u);
        part[threadIdx.x] = s;
        __syncthreads();
        if (threadIdx.x == 0) {
            u32 cum = 0; int seg = 255;
            for (; seg > 0; --seg) {
                if (cum + part[seg] >= P_PRE) break;
                cum += part[seg];
            }
            u32 cgt = cum; int bA = seg * 16; u32 hbA = 0;
            for (int b = seg * 16 + 15; b >= seg * 16; --b) {
                u32 hb = atomicAdd(&hh[b], 0u);
                if (cgt + hb >= P_PRE) { bA = b; hbA = hb; break; }
                cgt += hb;
            }
            meta[im * 16 + 0] = (u32)bA;
            meta[im * 16 + 1] = cgt;
            if (cgt + hbA <= CAND_CAP) {
                meta[im * 16 + 2] = ((u32)bA) << 12;   // 24-bit threshold, pass-A only
                meta[im * 16 + 8] = 0u;                // needB = 0
            } else {
                meta[im * 16 + 8] = 1u;                // fallback: refine in pass B
            }
        }
        __syncthreads();
    }
}

// ---------------- pass B (fallback only): refine next 12 bits ----------------
__global__ void k_histB(const float* __restrict__ sc, u32* __restrict__ histB,
                        u32* __restrict__ meta) {
    int n = blockIdx.y;
    if (meta[n * 16 + 8] == 0u) return;            // pass A sufficed
    __shared__ u32 h[BINS];
    __shared__ u32 part[256];
    __shared__ u32 isLast;
    for (int i = threadIdx.x; i < BINS; i += 256) h[i] = 0;
    __syncthreads();
    u32 bA = meta[n * 16 + 0];
    const float4* s4 = (const float4*)(sc + (size_t)n * K_TOT);
    for (int i = blockIdx.x * 256 + threadIdx.x; i < K_TOT4; i += HIST_BLK * 256) {
        float4 v = s4[i];
        u32 k0 = fkey(v.x), k1 = fkey(v.y), k2 = fkey(v.z), k3 = fkey(v.w);
        if ((k0 >> 20) == bA) atomicAdd(&h[(k0 >> 8) & 0xFFFu], 1u);
        if ((k1 >> 20) == bA) atomicAdd(&h[(k1 >> 8) & 0xFFFu], 1u);
        if ((k2 >> 20) == bA) atomicAdd(&h[(k2 >> 8) & 0xFFFu], 1u);
        if ((k3 >> 20) == bA) atomicAdd(&h[(k3 >> 8) & 0xFFFu], 1u);
    }
    __syncthreads();
    for (int i = threadIdx.x; i < BINS; i += 256) {
        u32 v = h[i];
        if (v) atomicAdd(&histB[n * BINS + i], v);
    }
    __threadfence();
    if (threadIdx.x == 0)
        isLast = (atomicAdd(&meta[n * 16 + 7], 1u) == (u32)(HIST_BLK - 1)) ? 1u : 0u;
    __syncthreads();
    if (!isLast) return;
    {
        int im = n;
        u32* hh = histB + im * BINS;
        u32 s = 0;
        for (int b = threadIdx.x * 16; b < threadIdx.x * 16 + 16; ++b)
            s += atomicAdd(&hh[b], 0u);
        part[threadIdx.x] = s;
        __syncthreads();
        if (threadIdx.x == 0) {
            u32 cum = meta[im * 16 + 1];
            int seg = 255;
            for (; seg > 0; --seg) {
                if (cum + part[seg] >= P_PRE) break;
                cum += part[seg];
            }
            int bB = seg * 16;
            for (int b = seg * 16 + 15; b >= seg * 16; --b) {
                u32 hb = atomicAdd(&hh[b], 0u);
                if (cum + hb >= P_PRE) { bB = b; break; }
                cum += hb;
            }
            meta[im * 16 + 2] = (meta[im * 16 + 0] << 12) | (u32)bB;
        }
    }
}

// ---------------- compaction: block-aggregated allocation (wave scan) --------
__global__ void __launch_bounds__(256) k_compact(const float* __restrict__ sc,
                                                 u32* __restrict__ meta,
                                                 u64* __restrict__ cand) {
    int n = blockIdx.y;
    int tid = threadIdx.x;
    int lane = tid & 63, w = tid >> 6;
    int i4 = blockIdx.x * 256 + tid;
    u32 thr = meta[n * 16 + 2];
    float vv[4] = {0.f, 0.f, 0.f, 0.f};
    u32 flags = 0;
    if (i4 < K_TOT4) {
        const float4* s4 = (const float4*)(sc + (size_t)n * K_TOT);
        float4 v = s4[i4];
        vv[0] = v.x; vv[1] = v.y; vv[2] = v.z; vv[3] = v.w;
        #pragma unroll
        for (int e = 0; e < 4; ++e)
            if ((fkey(vv[e]) >> 8) >= thr) flags |= 1u << e;
    }
    u32 cnt = (u32)__popc(flags);
    u32 incl = cnt;
    #pragma unroll
    for (int off = 1; off < 64; off <<= 1) {
        u32 v = __shfl_up(incl, (unsigned)off);
        if (lane >= off) incl += v;
    }
    __shared__ u32 wtot[4];
    __shared__ u32 baseS;
    if (lane == 63) wtot[w] = incl;
    __syncthreads();
    if (tid == 0) {
        u32 tot = wtot[0] + wtot[1] + wtot[2] + wtot[3];
        baseS = atomicAdd(&meta[n * 16 + 3], tot);
    }
    __syncthreads();
    if (!flags) return;
    u32 wbase = 0;
    for (int i = 0; i < w; ++i) wbase += wtot[i];
    u32 pos = baseS + wbase + (incl - cnt);
    #pragma unroll
    for (int e = 0; e < 4; ++e) {
        if ((flags >> e) & 1u) {
            if (pos < CAND_CAP) {
                int el = i4 * 4 + e;               // memory order: a*HW + h*WW + w
                int a = el / HW;
                int r = el - a * HW;               // h*WW + w
                u32 idx = (u32)(r * A_NUM + a);    // logical order (h*W + w)*A + a
                cand[n * CAND_CAP + pos] = ((u64)fkey(vv[e]) << 32) | (u32)(~idx);
            }
            pos++;
        }
    }
}

// ---------------- fused exact-rank sort + decode ----------------
__global__ void __launch_bounds__(256) k_rankdec(
        const u64* __restrict__ cand, const u32* __restrict__ meta,
        const float* __restrict__ bbox, const float* __restrict__ iminfo,
        const float* __restrict__ anchors,
        float* __restrict__ topk_sc, float4* __restrict__ bbox4,
        u32* __restrict__ bval) {
    int n = blockIdx.y;
    u32 cnt = meta[n * 16 + 3];
    if (cnt > CAND_CAP) cnt = CAND_CAP;
    int base = blockIdx.x * 64;
    if (base >= (int)cnt) return;                  // uniform per block
    __shared__ u64 sk[CAND_CAP];                   // 64 KiB
    __shared__ u32 pr[4][64];
    int tid = threadIdx.x, lane = tid & 63, w = tid >> 6;
    int cntPad = (int)((cnt + 7u) & ~7u);
    const u64* cn = cand + (size_t)n * CAND_CAP;
    for (int i = tid; i < cntPad; i += 256)
        sk[i] = (i < (int)cnt) ? cn[i] : 0ull;     // pad 0 < any real key (bit63 set)
    __syncthreads();
    int myi = base + lane;
    u64 mykey = (myi < (int)cnt) ? sk[myi] : 0ull;
    int stride = ((cntPad >> 2) + 7) & ~7;         // per-wave key range, mult of 8
    int j0 = w * stride;
    int j1 = min(j0 + stride, cntPad);
    int rank = 0;
    for (int j = j0; j < j1; j += 8) {
        u64 k0 = sk[j + 0], k1 = sk[j + 1], k2 = sk[j + 2], k3 = sk[j + 3];
        u64 k4 = sk[j + 4], k5 = sk[j + 5], k6 = sk[j + 6], k7 = sk[j + 7];
        rank += (int)(k0 > mykey) + (int)(k1 > mykey)
              + (int)(k2 > mykey) + (int)(k3 > mykey)
              + (int)(k4 > mykey) + (int)(k5 > mykey)
              + (int)(k6 > mykey) + (int)(k7 > mykey);
    }
    pr[w][lane] = (u32)rank;
    __syncthreads();
    if (w != 0 || myi >= (int)cnt) return;
    int r = (int)(pr[0][lane] + pr[1][lane] + pr[2][lane] + pr[3][lane]);
    if (r >= P_PRE) return;
    u32 idx = ~(u32)(mykey & 0xFFFFFFFFull);
    float score = __uint_as_float((u32)(mykey >> 32) ^ 0x80000000u);
    topk_sc[n * P_PRE + r] = score;
    // ---- inline decode (identical expressions to the reference) ----
    int a = (int)(idx % A_NUM);
    int cell = (int)(idx / A_NUM);
    int ww = cell % WW, hh = cell / WW;
    float ax1 = anchors[a * 4 + 0] + FSTRIDE * (float)ww;
    float ay1 = anchors[a * 4 + 1] + FSTRIDE * (float)hh;
    float ax2 = anchors[a * 4 + 2] + FSTRIDE * (float)ww;
    float ay2 = anchors[a * 4 + 3] + FSTRIDE * (float)hh;
    float ws = ax2 - ax1 + 1.0f;
    float hs = ay2 - ay1 + 1.0f;
    float cx = ax1 + 0.5f * ws;
    float cy = ay1 + 0.5f * hs;
    const float* bb = bbox + (size_t)n * 4 * A_NUM * HW + hh * WW + ww;
    float dx = bb[(4 * a + 0) * HW];
    float dy = bb[(4 * a + 1) * HW];
    float dw = fminf(bb[(4 * a + 2) * HW], BBOX_CLIP);
    float dh = fminf(bb[(4 * a + 3) * HW], BBOX_CLIP);
    float pcx = dx * ws + cx, pcy = dy * hs + cy;
    float pw = expf(dw) * ws, ph = expf(dh) * hs;
    float x1 = pcx - 0.5f * pw;
    float y1 = pcy - 0.5f * ph;
    float x2 = pcx + 0.5f * pw - 1.0f;
    float y2 = pcy + 0.5f * ph - 1.0f;
    float im_h = iminfo[n * 3 + 0], im_w = iminfo[n * 3 + 1], iscale = iminfo[n * 3 + 2];
    x1 = fminf(fmaxf(x1, 0.0f), im_w - 1.0f);
    y1 = fminf(fmaxf(y1, 0.0f), im_h - 1.0f);
    x2 = fminf(fmaxf(x2, 0.0f), im_w - 1.0f);
    y2 = fminf(fmaxf(y2, 0.0f), im_h - 1.0f);
    float wss = x2 - x1 + 1.0f, hss = y2 - y1 + 1.0f;
    float xc = x1 + wss * 0.5f, yc = y1 + hss * 0.5f;
    float ms = MIN_SZ * iscale;
    bool valid = (wss >= ms) && (hss >= ms) && (xc < im_w) && (yc < im_h);
    float4 b; b.x = x1; b.y = y1; b.z = x2; b.w = y2;
    bbox4[n * P_PRE + r] = b;
    bval[n * P_PRE + r] = valid ? 1u : 0u;
}

// ---------------- stable partition + area precompute (wave scan) -------------
__global__ void __launch_bounds__(1024) k_partition(
        const float4* __restrict__ bbox4,
        const float* __restrict__ bsc, const u32* __restrict__ bval,
        float4* __restrict__ sbox, float* __restrict__ ssc,
        float* __restrict__ sarea, u32* __restrict__ meta) {
    int n = blockIdx.x;
    int t = threadIdx.x;
    int lane = t & 63, w = t >> 6;
    int base = t * 6;
    u32 cnt = 0;
    if (base < P_PRE)
        for (int e = 0; e < 6; ++e) cnt += bval[n * P_PRE + base + e];
    u32 incl = cnt;
    #pragma unroll
    for (int off = 1; off < 64; off <<= 1) {
        u32 v = __shfl_up(incl, (unsigned)off);
        if (lane >= off) incl += v;
    }
    __shared__ u32 wtot[16];
    if (lane == 63) wtot[w] = incl;
    __syncthreads();
    u32 nv = 0, wbase = 0;
    #pragma unroll
    for (int i = 0; i < 16; ++i) {
        u32 x = wtot[i];
        if (i < w) wbase += x;
        nv += x;
    }
    u32 excl = wbase + (incl - cnt);
    if (t == 0) meta[n * 16 + 4] = nv;
    if (base < P_PRE) {
        u32 vseen = excl;
        for (int e = 0; e < 6; ++e) {
            int g = base + e;
            int src = n * P_PRE + g;
            u32 dst;
            if (bval[src]) { dst = vseen; vseen++; }
            else { dst = nv + (u32)g - vseen; }
            int d = n * P_PRE + (int)dst;
            float4 b = bbox4[src];
            sbox[d] = b;
            ssc[d] = bsc[src];
            sarea[d] = (b.z - b.x + 1.0f) * (b.w - b.y + 1.0f);  // ref expression
        }
    }
}

// ---------------- suppression mask, ci-major with LDS row-panel ----------------
__global__ void __launch_bounds__(256) k_mask(const float4* __restrict__ sbox,
                                              const float* __restrict__ sarea,
                                              u64* __restrict__ mask,
                                              u64* __restrict__ selfmask) {
    int n = blockIdx.y;
    int rem = blockIdx.x;
    int ci = 0;
    while (true) {
        int g = (NWORDS - ci + 7) >> 3;
        if (rem < g) break;
        rem -= g;
        ++ci;
    }
    int cjBase = ci + (rem << 3);
    int lane = threadIdx.x & 63;
    int wv = threadIdx.x >> 6;
    __shared__ float4 sbi[64];
    __shared__ float sar[64];
    const float4* pb = sbox + n * P_PRE;
    const float* pa = sarea + n * P_PRE;
    if (threadIdx.x < 64) {
        int ic = min(ci * 64 + (int)threadIdx.x, P_PRE - 1);
        sbi[threadIdx.x] = pb[ic];
        sar[threadIdx.x] = pa[ic];
    }
    __syncthreads();
    #pragma unroll
    for (int sub = 0; sub < 2; ++sub) {
        int cj = cjBase + wv + sub * 4;
        if (cj >= NWORDS) continue;
        int j = cj * 64 + lane;
        int jc = min(j, P_PRE - 1);
        float4 bj = pb[jc];
        float arj = pa[jc];
        if (cj == ci) {
            u64 sm = 0;
            #pragma unroll 8
            for (int r = 0; r < 64; ++r) {
                bool sup = iou_gt(sar[r], arj, sbi[r], bj) && (r < lane);
                sm |= ((u64)sup) << r;
            }
            if (j < P_PRE) selfmask[(size_t)n * P_PRE + j] = sm;
        } else {
            u64 myword = 0;
            #pragma unroll 8
            for (int r = 0; r < 64; ++r) {
                u64 wrd = __ballot(iou_gt(sar[r], arj, sbi[r], bj));
                if (lane == r) myword = wrd;
            }
            int i = ci * 64 + lane;                // lane holds row i's word
            if (i < P_PRE)
                mask[((size_t)n * P_PRE + i) * NWORDS + cj] = myword;
        }
    }
}

// ---------------- greedy NMS scan: pair-parallel scatter ----------------
__global__ void __launch_bounds__(1024) k_scan(
        const u64* __restrict__ mask, const u64* __restrict__ selfmask,
        const float4* __restrict__ sbox, const float* __restrict__ ssc,
        const u32* __restrict__ meta, float* __restrict__ out) {
    int n = blockIdx.x;
    int tid = threadIdx.x;
    int lane = tid & 63;
    int wv = tid >> 6;
    __shared__ u64 rem[NWORDS];
    __shared__ u64 smb[2][64];
    __shared__ u64 sA;
    __shared__ u32 rowsS[64];
    __shared__ int nkS;
    __shared__ u32 kidx[R_POST];
    __shared__ int keptS;
    u32 nv = meta[n * 16 + 4];
    const u64* mrow = mask + (size_t)n * P_PRE * NWORDS;
    const u64* smk = selfmask + (size_t)n * P_PRE;
    for (int c = tid; c < NWORDS; c += 1024) {
        int b0 = c * 64;
        rem[c] = ((u32)b0 >= nv) ? ~0ull
               : (((u32)(nv - b0) >= 64u) ? 0ull : ((~0ull) << (nv - b0)));
    }
    if (wv == 1) smb[0][lane] = smk[lane];         // chunk 0 selfmask
    if (tid == 0) keptS = 0;
    __syncthreads();
    for (int c = 0; c < NWORDS; ++c) {
        if (wv == 1 && (c + 1) < NWORDS) {
            int j = (c + 1) * 64 + lane;
            smb[(c + 1) & 1][lane] = (j < P_PRE) ? smk[j] : 0ull;
        }
        if (wv == 0) {
            u64 A = ~rem[c];
            if (A) {
                u64 sm = smb[c & 1][lane];
                u64 below = (1ull << lane) - 1ull;
                bool cand = ((A >> lane) & 1ull) != 0ull;
                while (true) {                     // fixed-point greedy closure
                    bool sup = (sm & A & below) != 0ull;
                    u64 nA = __ballot(cand && !sup);
                    if (nA == A) break;
                    A = nA;
                }
                int kept = keptS;                  // wave-uniform read
                if ((A >> lane) & 1ull) {
                    int rk = (int)__popcll(A & below);
                    int pos = kept + rk;
                    if (pos < R_POST) kidx[pos] = (u32)(c * 64 + lane);
                    rowsS[rk] = (u32)lane;
                }
                if (lane == 0) {
                    keptS = kept + (int)__popcll(A);
                    nkS = (int)__popcll(A);
                    sA = A;
                }
            } else if (lane == 0) { sA = 0; nkS = 0; }
        }
        __syncthreads();
        if (keptS >= R_POST) break;                // uniform; prefix property
        if (sA) {
            int colSlot = tid & 127;
            int rg = tid >> 7;                     // 8 row groups
            int col = c + 1 + colSlot;
            int nk = nkS;
            if (col < NWORDS && rg < nk) {
                int jbase = c * 64;
                u64 acc = 0;
                for (int r = rg; r < nk; r += 32) {
                    int r1 = r + 8, r2 = r + 16, r3 = r + 24;
                    u64 v0 = mrow[(size_t)(jbase + (int)rowsS[r]) * NWORDS + col];
                    u64 v1 = (r1 < nk) ? mrow[(size_t)(jbase + (int)rowsS[r1]) * NWORDS + col] : 0ull;
                    u64 v2 = (r2 < nk) ? mrow[(size_t)(jbase + (int)rowsS[r2]) * NWORDS + col] : 0ull;
                    u64 v3 = (r3 < nk) ? mrow[(size_t)(jbase + (int)rowsS[r3]) * NWORDS + col] : 0ull;
                    acc |= v0 | v1 | v2 | v3;
                }
                if (acc) atomicOr(&rem[col], acc);
            }
        }
        __syncthreads();
    }
    __syncthreads();
    int kept = keptS;
    for (int r = tid; r < R_POST; r += 1024) {
        float4 b = make_float4(0.f, 0.f, 0.f, 0.f);
        float s = 0.f;
        if (r < kept) {
            u32 i = kidx[r];
            b = sbox[n * P_PRE + (int)i];
            s = ssc[n * P_PRE + (int)i];
        }
        float* o = out + (size_t)(n * R_POST + r) * 6;
        o[0] = (float)n;                   // batch index NOT masked in reference
        o[1] = b.x; o[2] = b.y; o[3] = b.z; o[4] = b.w; o[5] = s;
    }
}

extern "C" void kernel_launch(void* const* d_in, const int* in_sizes, int n_in,
                              void* d_out, int out_size, void* d_ws, size_t ws_size,
                              hipStream_t stream) {
    const float* scores  = (const float*)d_in[0];
    const float* bbox    = (const float*)d_in[1];
    const float* iminfo  = (const float*)d_in[2];
    const float* anchors = (const float*)d_in[3];
    float* out = (float*)d_out;

    char* ws = (char*)d_ws;
    size_t off = 0;
    u32* histA = (u32*)(ws + off); off += (size_t)N_IMG * BINS * 4;    // 32768
    u32* histB = (u32*)(ws + off); off += (size_t)N_IMG * BINS * 4;    // 32768
    u32* meta  = (u32*)(ws + off); off += (size_t)N_IMG * 16 * 4;      // 128
    u64* cand      = (u64*)(ws + off);   off += (size_t)N_IMG * CAND_CAP * 8;
    float* topk_sc = (float*)(ws + off); off += (size_t)N_IMG * P_PRE * 4;
    float4* bbox4 = (float4*)(ws + off); off += (size_t)N_IMG * P_PRE * 16;
    u32* bval  = (u32*)(ws + off);       off += (size_t)N_IMG * P_PRE * 4;
    float4* sbox = (float4*)(ws + off);  off += (size_t)N_IMG * P_PRE * 16;
    float* ssc = (float*)(ws + off);     off += (size_t)N_IMG * P_PRE * 4;
    float* sarea = (float*)(ws + off);   off += (size_t)N_IMG * P_PRE * 4;
    u64* selfmask = (u64*)(ws + off);    off += (size_t)N_IMG * P_PRE * 8;
    u64* mask = (u64*)(ws + off);        off += (size_t)N_IMG * P_PRE * NWORDS * 8;
    (void)ws_size; (void)in_sizes; (void)n_in; (void)out_size;

    k_zero<<<(ZERO_WORDS + 1023) / 1024, 1024, 0, stream>>>((u32*)d_ws);

    dim3 gHist(HIST_BLK, N_IMG);
    k_histA<<<gHist, 256, 0, stream>>>(scores, histA, meta);
    k_histB<<<gHist, 256, 0, stream>>>(scores, histB, meta);
    dim3 gComp((K_TOT4 + 255) / 256, N_IMG);
    k_compact<<<gComp, 256, 0, stream>>>(scores, meta, cand);
    dim3 gRank(CAND_CAP / 64, N_IMG);
    k_rankdec<<<gRank, 256, 0, stream>>>(cand, meta, bbox, iminfo, anchors,
                                         topk_sc, bbox4, bval);
    k_partition<<<N_IMG, 1024, 0, stream>>>(bbox4, topk_sc, bval, sbox, ssc, sarea, meta);
    dim3 gMask(MASK_BLOCKS, N_IMG);
    k_mask<<<gMask, 256, 0, stream>>>(sbox, sarea, mask, selfmask);
    k_scan<<<N_IMG, 1024, 0, stream>>>(mask, selfmask, sbox, ssc, meta, out);
}

// Round 18
// 143.238 us; speedup vs baseline: 1.7628x; 1.2371x over previous
//
#include <hip/hip_runtime.h>
#include <stdint.h>

#define N_IMG 2
#define A_NUM 15
#define HH 200
#define WW 200
#define HW 40000          // HH*WW
#define K_TOT 600000      // A_NUM*HW
#define K_TOT4 150000     // K_TOT/4
#define P_PRE 6000
#define R_POST 1000
#define NMS_T 0.7f
#define MIN_SZ 16.0f
#define FSTRIDE 16.0f
#define BBOX_CLIP 4.135166556742356f   // log(1000/16)
#define CAND_CAP 8192
#define NWORDS 94         // ceil(6000/64)
#define BINS 4096
#define HIST_BLK 64       // blocks per image for k_histA/k_histB (R15 value)
// k_mask blocks per image: sum over ci of ceil((NWORDS-ci)/8) = 600
#define MASK_BLOCKS 600
// words to zero each launch: histA + histB + meta
#define ZERO_WORDS (N_IMG * BINS * 2 + N_IMG * 16)   // 16416
// Exact threshold: fl32(inter/union) > 0.7f  <=>  inter/union >= MID_T
#define MID_T 0.7000000178813934326171875

typedef unsigned long long u64;
typedef uint32_t u32;

// Exact full-precision key (used for final ranking; order-exact).
__device__ __forceinline__ u32 fkey(float s) {
    return __float_as_uint(s) | 0x80000000u;
}

// Monotone 24-bit SELECTION key: uniform [0,1) scores spread evenly over all
// 4096 hist bins (vs 8 bins for float-bit keys) -> pass-A suffices and LDS
// atomic contention collapses. Monotone non-decreasing => {hkey >= thr} is an
// up-set in score order => selected set is a superset of the exact top-P.
// Final ordering uses the exact fkey, so output is bit-identical.
__device__ __forceinline__ u32 hkey(float s) {
    float c = fminf(fmaxf(s, 0.0f), 0.99999994f);
    return (u32)(c * 16777216.0f);       // [0, 2^24)
}

// IoU decision, bit-identical to fl32(inter/(ar+arj-inter)) > 0.7f.
__device__ __forceinline__ bool iou_gt(float ar, float arj,
                                       const float4& bi, const float4& bj) {
    float xx1 = fmaxf(bi.x, bj.x);
    float yy1 = fmaxf(bi.y, bj.y);
    float xx2 = fminf(bi.z, bj.z);
    float yy2 = fminf(bi.w, bj.w);
    float iw = fmaxf(xx2 - xx1 + 1.0f, 0.0f);
    float ih = fmaxf(yy2 - yy1 + 1.0f, 0.0f);
    float inter = iw * ih;
    float uni = (ar + arj) - inter;          // same op order as reference
    return (double)inter >= MID_T * (double)uni;
}

// ---------------- workspace zeroing ----------------
__global__ void k_zero(u32* __restrict__ w) {
    int i = blockIdx.x * 1024 + threadIdx.x;
    if (i < ZERO_WORDS) w[i] = 0u;
}

// ---------------- pass A: 12-bit hkey histogram + last-block findA ----------
__global__ void k_histA(const float* __restrict__ sc, u32* __restrict__ histA,
                        u32* __restrict__ meta) {
    int n = blockIdx.y;
    __shared__ u32 h[BINS];
    __shared__ u32 part[256];
    __shared__ u32 isLast;
    for (int i = threadIdx.x; i < BINS; i += 256) h[i] = 0;
    __syncthreads();
    const float4* s4 = (const float4*)(sc + (size_t)n * K_TOT);
    for (int i = blockIdx.x * 256 + threadIdx.x; i < K_TOT4; i += HIST_BLK * 256) {
        float4 v = s4[i];
        atomicAdd(&h[hkey(v.x) >> 12], 1u);
        atomicAdd(&h[hkey(v.y) >> 12], 1u);
        atomicAdd(&h[hkey(v.z) >> 12], 1u);
        atomicAdd(&h[hkey(v.w) >> 12], 1u);
    }
    __syncthreads();
    for (int i = threadIdx.x; i < BINS; i += 256) {
        u32 v = h[i];
        if (v) atomicAdd(&histA[n * BINS + i], v);
    }
    __threadfence();
    if (threadIdx.x == 0)
        isLast = (atomicAdd(&meta[6], 1u) == (u32)(HIST_BLK * N_IMG - 1)) ? 1u : 0u;
    __syncthreads();
    if (!isLast) return;
    for (int im = 0; im < N_IMG; ++im) {
        u32* hh = histA + im * BINS;
        u32 s = 0;
        for (int b = threadIdx.x * 16; b < threadIdx.x * 16 + 16; ++b)
            s += atomicAdd(&hh[b], 0u);
        part[threadIdx.x] = s;
        __syncthreads();
        if (threadIdx.x == 0) {
            u32 cum = 0; int seg = 255;
            for (; seg > 0; --seg) {
                if (cum + part[seg] >= P_PRE) break;
                cum += part[seg];
            }
            u32 cgt = cum; int bA = seg * 16; u32 hbA = 0;
            for (int b = seg * 16 + 15; b >= seg * 16; --b) {
                u32 hb = atomicAdd(&hh[b], 0u);
                if (cgt + hb >= P_PRE) { bA = b; hbA = hb; break; }
                cgt += hb;
            }
            meta[im * 16 + 0] = (u32)bA;
            meta[im * 16 + 1] = cgt;
            if (cgt + hbA <= CAND_CAP) {
                meta[im * 16 + 2] = ((u32)bA) << 12;   // 24-bit hkey threshold
                meta[im * 16 + 8] = 0u;                // needB = 0 (uniform: always)
            } else {
                meta[im * 16 + 8] = 1u;                // fallback: refine in pass B
            }
        }
        __syncthreads();
    }
}

// ---------------- pass B (fallback only): refine low 12 hkey bits ------------
__global__ void k_histB(const float* __restrict__ sc, u32* __restrict__ histB,
                        u32* __restrict__ meta) {
    int n = blockIdx.y;
    if (meta[n * 16 + 8] == 0u) return;            // pass A sufficed
    __shared__ u32 h[BINS];
    __shared__ u32 part[256];
    __shared__ u32 isLast;
    for (int i = threadIdx.x; i < BINS; i += 256) h[i] = 0;
    __syncthreads();
    u32 bA = meta[n * 16 + 0];
    const float4* s4 = (const float4*)(sc + (size_t)n * K_TOT);
    for (int i = blockIdx.x * 256 + threadIdx.x; i < K_TOT4; i += HIST_BLK * 256) {
        float4 v = s4[i];
        u32 k0 = hkey(v.x), k1 = hkey(v.y), k2 = hkey(v.z), k3 = hkey(v.w);
        if ((k0 >> 12) == bA) atomicAdd(&h[k0 & 0xFFFu], 1u);
        if ((k1 >> 12) == bA) atomicAdd(&h[k1 & 0xFFFu], 1u);
        if ((k2 >> 12) == bA) atomicAdd(&h[k2 & 0xFFFu], 1u);
        if ((k3 >> 12) == bA) atomicAdd(&h[k3 & 0xFFFu], 1u);
    }
    __syncthreads();
    for (int i = threadIdx.x; i < BINS; i += 256) {
        u32 v = h[i];
        if (v) atomicAdd(&histB[n * BINS + i], v);
    }
    __threadfence();
    if (threadIdx.x == 0)
        isLast = (atomicAdd(&meta[n * 16 + 7], 1u) == (u32)(HIST_BLK - 1)) ? 1u : 0u;
    __syncthreads();
    if (!isLast) return;
    {
        int im = n;
        u32* hh = histB + im * BINS;
        u32 s = 0;
        for (int b = threadIdx.x * 16; b < threadIdx.x * 16 + 16; ++b)
            s += atomicAdd(&hh[b], 0u);
        part[threadIdx.x] = s;
        __syncthreads();
        if (threadIdx.x == 0) {
            u32 cum = meta[im * 16 + 1];
            int seg = 255;
            for (; seg > 0; --seg) {
                if (cum + part[seg] >= P_PRE) break;
                cum += part[seg];
            }
            int bB = seg * 16;
            for (int b = seg * 16 + 15; b >= seg * 16; --b) {
                u32 hb = atomicAdd(&hh[b], 0u);
                if (cum + hb >= P_PRE) { bB = b; break; }
                cum += hb;
            }
            meta[im * 16 + 2] = (meta[im * 16 + 0] << 12) | (u32)bB;
        }
    }
}

// ---------------- compaction: block-aggregated allocation (wave scan) --------
__global__ void __launch_bounds__(256) k_compact(const float* __restrict__ sc,
                                                 u32* __restrict__ meta,
                                                 u64* __restrict__ cand) {
    int n = blockIdx.y;
    int tid = threadIdx.x;
    int lane = tid & 63, w = tid >> 6;
    int i4 = blockIdx.x * 256 + tid;
    u32 thr = meta[n * 16 + 2];
    float vv[4] = {0.f, 0.f, 0.f, 0.f};
    u32 flags = 0;
    if (i4 < K_TOT4) {
        const float4* s4 = (const float4*)(sc + (size_t)n * K_TOT);
        float4 v = s4[i4];
        vv[0] = v.x; vv[1] = v.y; vv[2] = v.z; vv[3] = v.w;
        #pragma unroll
        for (int e = 0; e < 4; ++e)
            if (hkey(vv[e]) >= thr) flags |= 1u << e;
    }
    u32 cnt = (u32)__popc(flags);
    u32 incl = cnt;
    #pragma unroll
    for (int off = 1; off < 64; off <<= 1) {
        u32 v = __shfl_up(incl, (unsigned)off);
        if (lane >= off) incl += v;
    }
    __shared__ u32 wtot[4];
    __shared__ u32 baseS;
    if (lane == 63) wtot[w] = incl;
    __syncthreads();
    if (tid == 0) {
        u32 tot = wtot[0] + wtot[1] + wtot[2] + wtot[3];
        baseS = atomicAdd(&meta[n * 16 + 3], tot);
    }
    __syncthreads();
    if (!flags) return;
    u32 wbase = 0;
    for (int i = 0; i < w; ++i) wbase += wtot[i];
    u32 pos = baseS + wbase + (incl - cnt);
    #pragma unroll
    for (int e = 0; e < 4; ++e) {
        if ((flags >> e) & 1u) {
            if (pos < CAND_CAP) {
                int el = i4 * 4 + e;               // memory order: a*HW + h*WW + w
                int a = el / HW;
                int r = el - a * HW;               // h*WW + w
                u32 idx = (u32)(r * A_NUM + a);    // logical order (h*W + w)*A + a
                cand[n * CAND_CAP + pos] = ((u64)fkey(vv[e]) << 32) | (u32)(~idx);
            }
            pos++;
        }
    }
}

// ---------------- fused exact-rank sort + decode ----------------
__global__ void __launch_bounds__(256) k_rankdec(
        const u64* __restrict__ cand, const u32* __restrict__ meta,
        const float* __restrict__ bbox, const float* __restrict__ iminfo,
        const float* __restrict__ anchors,
        float* __restrict__ topk_sc, float4* __restrict__ bbox4,
        u32* __restrict__ bval) {
    int n = blockIdx.y;
    u32 cnt = meta[n * 16 + 3];
    if (cnt > CAND_CAP) cnt = CAND_CAP;
    int base = blockIdx.x * 64;
    if (base >= (int)cnt) return;                  // uniform per block
    __shared__ u64 sk[CAND_CAP];                   // 64 KiB
    __shared__ u32 pr[4][64];
    int tid = threadIdx.x, lane = tid & 63, w = tid >> 6;
    int cntPad = (int)((cnt + 7u) & ~7u);
    const u64* cn = cand + (size_t)n * CAND_CAP;
    for (int i = tid; i < cntPad; i += 256)
        sk[i] = (i < (int)cnt) ? cn[i] : 0ull;     // pad 0 < any real key (bit63 set)
    __syncthreads();
    int myi = base + lane;
    u64 mykey = (myi < (int)cnt) ? sk[myi] : 0ull;
    int stride = ((cntPad >> 2) + 7) & ~7;         // per-wave key range, mult of 8
    int j0 = w * stride;
    int j1 = min(j0 + stride, cntPad);
    int rank = 0;
    for (int j = j0; j < j1; j += 8) {
        u64 k0 = sk[j + 0], k1 = sk[j + 1], k2 = sk[j + 2], k3 = sk[j + 3];
        u64 k4 = sk[j + 4], k5 = sk[j + 5], k6 = sk[j + 6], k7 = sk[j + 7];
        rank += (int)(k0 > mykey) + (int)(k1 > mykey)
              + (int)(k2 > mykey) + (int)(k3 > mykey)
              + (int)(k4 > mykey) + (int)(k5 > mykey)
              + (int)(k6 > mykey) + (int)(k7 > mykey);
    }
    pr[w][lane] = (u32)rank;
    __syncthreads();
    if (w != 0 || myi >= (int)cnt) return;
    int r = (int)(pr[0][lane] + pr[1][lane] + pr[2][lane] + pr[3][lane]);
    if (r >= P_PRE) return;
    u32 idx = ~(u32)(mykey & 0xFFFFFFFFull);
    float score = __uint_as_float((u32)(mykey >> 32) ^ 0x80000000u);
    topk_sc[n * P_PRE + r] = score;
    // ---- inline decode (identical expressions to the reference) ----
    int a = (int)(idx % A_NUM);
    int cell = (int)(idx / A_NUM);
    int ww = cell % WW, hh = cell / WW;
    float ax1 = anchors[a * 4 + 0] + FSTRIDE * (float)ww;
    float ay1 = anchors[a * 4 + 1] + FSTRIDE * (float)hh;
    float ax2 = anchors[a * 4 + 2] + FSTRIDE * (float)ww;
    float ay2 = anchors[a * 4 + 3] + FSTRIDE * (float)hh;
    float ws = ax2 - ax1 + 1.0f;
    float hs = ay2 - ay1 + 1.0f;
    float cx = ax1 + 0.5f * ws;
    float cy = ay1 + 0.5f * hs;
    const float* bb = bbox + (size_t)n * 4 * A_NUM * HW + hh * WW + ww;
    float dx = bb[(4 * a + 0) * HW];
    float dy = bb[(4 * a + 1) * HW];
    float dw = fminf(bb[(4 * a + 2) * HW], BBOX_CLIP);
    float dh = fminf(bb[(4 * a + 3) * HW], BBOX_CLIP);
    float pcx = dx * ws + cx, pcy = dy * hs + cy;
    float pw = expf(dw) * ws, ph = expf(dh) * hs;
    float x1 = pcx - 0.5f * pw;
    float y1 = pcy - 0.5f * ph;
    float x2 = pcx + 0.5f * pw - 1.0f;
    float y2 = pcy + 0.5f * ph - 1.0f;
    float im_h = iminfo[n * 3 + 0], im_w = iminfo[n * 3 + 1], iscale = iminfo[n * 3 + 2];
    x1 = fminf(fmaxf(x1, 0.0f), im_w - 1.0f);
    y1 = fminf(fmaxf(y1, 0.0f), im_h - 1.0f);
    x2 = fminf(fmaxf(x2, 0.0f), im_w - 1.0f);
    y2 = fminf(fmaxf(y2, 0.0f), im_h - 1.0f);
    float wss = x2 - x1 + 1.0f, hss = y2 - y1 + 1.0f;
    float xc = x1 + wss * 0.5f, yc = y1 + hss * 0.5f;
    float ms = MIN_SZ * iscale;
    bool valid = (wss >= ms) && (hss >= ms) && (xc < im_w) && (yc < im_h);
    float4 b; b.x = x1; b.y = y1; b.z = x2; b.w = y2;
    bbox4[n * P_PRE + r] = b;
    bval[n * P_PRE + r] = valid ? 1u : 0u;
}

// ---------------- stable partition + area precompute (wave scan) -------------
__global__ void __launch_bounds__(1024) k_partition(
        const float4* __restrict__ bbox4,
        const float* __restrict__ bsc, const u32* __restrict__ bval,
        float4* __restrict__ sbox, float* __restrict__ ssc,
        float* __restrict__ sarea, u32* __restrict__ meta) {
    int n = blockIdx.x;
    int t = threadIdx.x;
    int lane = t & 63, w = t >> 6;
    int base = t * 6;
    u32 cnt = 0;
    if (base < P_PRE)
        for (int e = 0; e < 6; ++e) cnt += bval[n * P_PRE + base + e];
    u32 incl = cnt;
    #pragma unroll
    for (int off = 1; off < 64; off <<= 1) {
        u32 v = __shfl_up(incl, (unsigned)off);
        if (lane >= off) incl += v;
    }
    __shared__ u32 wtot[16];
    if (lane == 63) wtot[w] = incl;
    __syncthreads();
    u32 nv = 0, wbase = 0;
    #pragma unroll
    for (int i = 0; i < 16; ++i) {
        u32 x = wtot[i];
        if (i < w) wbase += x;
        nv += x;
    }
    u32 excl = wbase + (incl - cnt);
    if (t == 0) meta[n * 16 + 4] = nv;
    if (base < P_PRE) {
        u32 vseen = excl;
        for (int e = 0; e < 6; ++e) {
            int g = base + e;
            int src = n * P_PRE + g;
            u32 dst;
            if (bval[src]) { dst = vseen; vseen++; }
            else { dst = nv + (u32)g - vseen; }
            int d = n * P_PRE + (int)dst;
            float4 b = bbox4[src];
            sbox[d] = b;
            ssc[d] = bsc[src];
            sarea[d] = (b.z - b.x + 1.0f) * (b.w - b.y + 1.0f);  // ref expression
        }
    }
}

// ---------------- suppression mask, ci-major with LDS row-panel ----------------
__global__ void __launch_bounds__(256) k_mask(const float4* __restrict__ sbox,
                                              const float* __restrict__ sarea,
                                              u64* __restrict__ mask,
                                              u64* __restrict__ selfmask) {
    int n = blockIdx.y;
    int rem = blockIdx.x;
    int ci = 0;
    while (true) {
        int g = (NWORDS - ci + 7) >> 3;
        if (rem < g) break;
        rem -= g;
        ++ci;
    }
    int cjBase = ci + (rem << 3);
    int lane = threadIdx.x & 63;
    int wv = threadIdx.x >> 6;
    __shared__ float4 sbi[64];
    __shared__ float sar[64];
    const float4* pb = sbox + n * P_PRE;
    const float* pa = sarea + n * P_PRE;
    if (threadIdx.x < 64) {
        int ic = min(ci * 64 + (int)threadIdx.x, P_PRE - 1);
        sbi[threadIdx.x] = pb[ic];
        sar[threadIdx.x] = pa[ic];
    }
    __syncthreads();
    #pragma unroll
    for (int sub = 0; sub < 2; ++sub) {
        int cj = cjBase + wv + sub * 4;
        if (cj >= NWORDS) continue;
        int j = cj * 64 + lane;
        int jc = min(j, P_PRE - 1);
        float4 bj = pb[jc];
        float arj = pa[jc];
        if (cj == ci) {
            u64 sm = 0;
            #pragma unroll 8
            for (int r = 0; r < 64; ++r) {
                bool sup = iou_gt(sar[r], arj, sbi[r], bj) && (r < lane);
                sm |= ((u64)sup) << r;
            }
            if (j < P_PRE) selfmask[(size_t)n * P_PRE + j] = sm;
        } else {
            u64 myword = 0;
            #pragma unroll 8
            for (int r = 0; r < 64; ++r) {
                u64 wrd = __ballot(iou_gt(sar[r], arj, sbi[r], bj));
                if (lane == r) myword = wrd;
            }
            int i = ci * 64 + lane;                // lane holds row i's word
            if (i < P_PRE)
                mask[((size_t)n * P_PRE + i) * NWORDS + cj] = myword;
        }
    }
}

// ---------------- greedy NMS scan: pair-parallel scatter ----------------
__global__ void __launch_bounds__(1024) k_scan(
        const u64* __restrict__ mask, const u64* __restrict__ selfmask,
        const float4* __restrict__ sbox, const float* __restrict__ ssc,
        const u32* __restrict__ meta, float* __restrict__ out) {
    int n = blockIdx.x;
    int tid = threadIdx.x;
    int lane = tid & 63;
    int wv = tid >> 6;
    __shared__ u64 rem[NWORDS];
    __shared__ u64 smb[2][64];
    __shared__ u64 sA;
    __shared__ u32 rowsS[64];
    __shared__ int nkS;
    __shared__ u32 kidx[R_POST];
    __shared__ int keptS;
    u32 nv = meta[n * 16 + 4];
    const u64* mrow = mask + (size_t)n * P_PRE * NWORDS;
    const u64* smk = selfmask + (size_t)n * P_PRE;
    for (int c = tid; c < NWORDS; c += 1024) {
        int b0 = c * 64;
        rem[c] = ((u32)b0 >= nv) ? ~0ull
               : (((u32)(nv - b0) >= 64u) ? 0ull : ((~0ull) << (nv - b0)));
    }
    if (wv == 1) smb[0][lane] = smk[lane];         // chunk 0 selfmask
    if (tid == 0) keptS = 0;
    __syncthreads();
    for (int c = 0; c < NWORDS; ++c) {
        if (wv == 1 && (c + 1) < NWORDS) {
            int j = (c + 1) * 64 + lane;
            smb[(c + 1) & 1][lane] = (j < P_PRE) ? smk[j] : 0ull;
        }
        if (wv == 0) {
            u64 A = ~rem[c];
            if (A) {
                u64 sm = smb[c & 1][lane];
                u64 below = (1ull << lane) - 1ull;
                bool cand = ((A >> lane) & 1ull) != 0ull;
                while (true) {                     // fixed-point greedy closure
                    bool sup = (sm & A & below) != 0ull;
                    u64 nA = __ballot(cand && !sup);
                    if (nA == A) break;
                    A = nA;
                }
                int kept = keptS;                  // wave-uniform read
                if ((A >> lane) & 1ull) {
                    int rk = (int)__popcll(A & below);
                    int pos = kept + rk;
                    if (pos < R_POST) kidx[pos] = (u32)(c * 64 + lane);
                    rowsS[rk] = (u32)lane;
                }
                if (lane == 0) {
                    keptS = kept + (int)__popcll(A);
                    nkS = (int)__popcll(A);
                    sA = A;
                }
            } else if (lane == 0) { sA = 0; nkS = 0; }
        }
        __syncthreads();
        if (keptS >= R_POST) break;                // uniform; prefix property
        if (sA) {
            int colSlot = tid & 127;
            int rg = tid >> 7;                     // 8 row groups
            int col = c + 1 + colSlot;
            int nk = nkS;
            if (col < NWORDS && rg < nk) {
                int jbase = c * 64;
                u64 acc = 0;
                for (int r = rg; r < nk; r += 32) {
                    int r1 = r + 8, r2 = r + 16, r3 = r + 24;
                    u64 v0 = mrow[(size_t)(jbase + (int)rowsS[r]) * NWORDS + col];
                    u64 v1 = (r1 < nk) ? mrow[(size_t)(jbase + (int)rowsS[r1]) * NWORDS + col] : 0ull;
                    u64 v2 = (r2 < nk) ? mrow[(size_t)(jbase + (int)rowsS[r2]) * NWORDS + col] : 0ull;
                    u64 v3 = (r3 < nk) ? mrow[(size_t)(jbase + (int)rowsS[r3]) * NWORDS + col] : 0ull;
                    acc |= v0 | v1 | v2 | v3;
                }
                if (acc) atomicOr(&rem[col], acc);
            }
        }
        __syncthreads();
    }
    __syncthreads();
    int kept = keptS;
    for (int r = tid; r < R_POST; r += 1024) {
        float4 b = make_float4(0.f, 0.f, 0.f, 0.f);
        float s = 0.f;
        if (r < kept) {
            u32 i = kidx[r];
            b = sbox[n * P_PRE + (int)i];
            s = ssc[n * P_PRE + (int)i];
        }
        float* o = out + (size_t)(n * R_POST + r) * 6;
        o[0] = (float)n;                   // batch index NOT masked in reference
        o[1] = b.x; o[2] = b.y; o[3] = b.z; o[4] = b.w; o[5] = s;
    }
}

extern "C" void kernel_launch(void* const* d_in, const int* in_sizes, int n_in,
                              void* d_out, int out_size, void* d_ws, size_t ws_size,
                              hipStream_t stream) {
    const float* scores  = (const float*)d_in[0];
    const float* bbox    = (const float*)d_in[1];
    const float* iminfo  = (const float*)d_in[2];
    const float* anchors = (const float*)d_in[3];
    float* out = (float*)d_out;

    char* ws = (char*)d_ws;
    size_t off = 0;
    u32* histA = (u32*)(ws + off); off += (size_t)N_IMG * BINS * 4;    // 32768
    u32* histB = (u32*)(ws + off); off += (size_t)N_IMG * BINS * 4;    // 32768
    u32* meta  = (u32*)(ws + off); off += (size_t)N_IMG * 16 * 4;      // 128
    u64* cand      = (u64*)(ws + off);   off += (size_t)N_IMG * CAND_CAP * 8;
    float* topk_sc = (float*)(ws + off); off += (size_t)N_IMG * P_PRE * 4;
    float4* bbox4 = (float4*)(ws + off); off += (size_t)N_IMG * P_PRE * 16;
    u32* bval  = (u32*)(ws + off);       off += (size_t)N_IMG * P_PRE * 4;
    float4* sbox = (float4*)(ws + off);  off += (size_t)N_IMG * P_PRE * 16;
    float* ssc = (float*)(ws + off);     off += (size_t)N_IMG * P_PRE * 4;
    float* sarea = (float*)(ws + off);   off += (size_t)N_IMG * P_PRE * 4;
    u64* selfmask = (u64*)(ws + off);    off += (size_t)N_IMG * P_PRE * 8;
    u64* mask = (u64*)(ws + off);        off += (size_t)N_IMG * P_PRE * NWORDS * 8;
    (void)ws_size; (void)in_sizes; (void)n_in; (void)out_size;

    k_zero<<<(ZERO_WORDS + 1023) / 1024, 1024, 0, stream>>>((u32*)d_ws);

    dim3 gHist(HIST_BLK, N_IMG);
    k_histA<<<gHist, 256, 0, stream>>>(scores, histA, meta);
    k_histB<<<gHist, 256, 0, stream>>>(scores, histB, meta);
    dim3 gComp((K_TOT4 + 255) / 256, N_IMG);
    k_compact<<<gComp, 256, 0, stream>>>(scores, meta, cand);
    dim3 gRank(CAND_CAP / 64, N_IMG);
    k_rankdec<<<gRank, 256, 0, stream>>>(cand, meta, bbox, iminfo, anchors,
                                         topk_sc, bbox4, bval);
    k_partition<<<N_IMG, 1024, 0, stream>>>(bbox4, topk_sc, bval, sbox, ssc, sarea, meta);
    dim3 gMask(MASK_BLOCKS, N_IMG);
    k_mask<<<gMask, 256, 0, stream>>>(sbox, sarea, mask, selfmask);
    k_scan<<<N_IMG, 1024, 0, stream>>>(mask, selfmask, sbox, ssc, meta, out);
}